// Round 1
// baseline (427.871 us; speedup 1.0000x reference)
//
#include <hip/hip_runtime.h>
#include <stdint.h>

#define NB 4
#define CC 64
#define VV 8192
#define WBK 128              // w-columns per block
#define KB 64                // v per K-chunk
#define NCHUNK (VV / KB)     // 128

typedef float  f32x4  __attribute__((ext_vector_type(4)));
typedef uint32_t u32x2 __attribute__((ext_vector_type(2)));
typedef uint32_t u32x4 __attribute__((ext_vector_type(4)));
typedef __bf16 bf16x8 __attribute__((ext_vector_type(8)));

// XOR-swizzled index into a [row][KB] bf16 tile: 16B granule ^= (row&7)
__device__ __forceinline__ int swz_idx(int row, int v) {
    return row * KB + ((((v >> 3) ^ row) & 7) << 3) + (v & 7);
}

__device__ __forceinline__ uint32_t pkbf(float a, float b) {
    union { __bf16 h[2]; uint32_t u; } t;
    t.h[0] = (__bf16)a; t.h[1] = (__bf16)b;
    return t.u;
}

__device__ __forceinline__ bf16x8 mkfrag(const __bf16* p, int row, int k0) {
    u32x2 lo = *(const u32x2*)(p + swz_idx(row, k0));
    u32x2 hi = *(const u32x2*)(p + swz_idx(row, k0 + 16));
    u32x4 u; u.x = lo.x; u.y = lo.y; u.z = hi.x; u.w = hi.y;
    return __builtin_bit_cast(bf16x8, u);
}

// K1: y[n,c,v] = b[c] + sum_c' W[c,c'] x[n,c',v], stored bf16 pre-swizzled:
// yws layout: [n][chunk t][c][swz(v&63)]  (matches K2's LDS image exactly)
__global__ __launch_bounds__(256) void k_y(const float* __restrict__ x,
                                           const float* __restrict__ Wg,
                                           const float* __restrict__ bg,
                                           __bf16* __restrict__ yws) {
    const int n  = blockIdx.x >> 4;                       // 16 blocks per n
    const int vp = (blockIdx.x & 15) * 256 + threadIdx.x; // v-pair id, 4096 per n
    const int v  = vp * 2;
    const float* xg = x + (size_t)n * CC * VV + v;

    float ax[CC], ay[CC];
    #pragma unroll
    for (int c = 0; c < CC; ++c) { float bb = bg[c]; ax[c] = bb; ay[c] = bb; }

    for (int cp = 0; cp < CC; ++cp) {
        float xv0 = xg[(size_t)cp * VV];
        float xv1 = xg[(size_t)cp * VV + 1];
        #pragma unroll
        for (int c = 0; c < CC; ++c) {
            float w = Wg[c * CC + cp];   // uniform -> scalar load
            ax[c] += w * xv0;
            ay[c] += w * xv1;
        }
    }
    const int t  = v >> 6;
    const int vv = v & 63;               // even
    __bf16* ydst = yws + (size_t)(n * NCHUNK + t) * CC * KB;
    #pragma unroll
    for (int c = 0; c < CC; ++c)
        *(uint32_t*)&ydst[swz_idx(c, vv)] = pkbf(ax[c], ay[c]);
}

// K2: per block (n, w0): out[n, 0:64, w0:w0+128] = y @ A, fused with A -> Acopy
__global__ __launch_bounds__(512, 1) void k_main(const float* __restrict__ A,
                                                 const __bf16* __restrict__ yws,
                                                 float* __restrict__ out,
                                                 float* __restrict__ Acopy,
                                                 int skipTail) {
    __shared__ __attribute__((aligned(16))) __bf16 a_sh[2][WBK * KB];
    __shared__ __attribute__((aligned(16))) __bf16 y_sh[2][CC * KB];

    const int tid  = threadIdx.x;
    const int n    = blockIdx.x >> 6;
    const int w0   = (blockIdx.x & 63) * WBK;

    const int wl = tid & 127;        // w-column owned for staging
    const int vq = tid >> 7;         // v quarter (16 rows each)

    const float* pA = A     + (size_t)n * VV * VV + (size_t)vq * 16 * VV + (size_t)w0 + wl;
    float*       pC = Acopy + (size_t)n * VV * VV + (size_t)vq * 16 * VV + (size_t)w0 + wl;
    const uint4* ysrc = (const uint4*)(yws + (size_t)n * NCHUNK * CC * KB);

    const int lane = tid & 63;
    const int wv   = tid >> 6;
    const int mrow = wv >> 2;        // 0..1 -> c-half
    const int ncol = wv & 3;         // 0..3 -> w 32-slice
    const int l15  = lane & 15;
    const int kq   = (lane >> 4) * 4;
    const int crow = mrow * 32 + l15;
    const int wcol = ncol * 32 + l15;

    f32x4 acc[2][2];
    #pragma unroll
    for (int i = 0; i < 2; ++i)
        #pragma unroll
        for (int j = 0; j < 2; ++j) acc[i][j] = (f32x4){0.f, 0.f, 0.f, 0.f};

    float av[16];
    uint4 yv;

    auto stage_load = [&](int tt) {
        #pragma unroll
        for (int r = 0; r < 16; ++r)
            av[r] = pA[(size_t)(tt * KB + r) * VV];
        yv = ysrc[(size_t)tt * 512 + tid];
    };
    auto stage_write = [&](int tt, int b) {
        if (!(skipTail && n == 3 && tt >= 126)) {
            #pragma unroll
            for (int r = 0; r < 16; ++r)
                pC[(size_t)(tt * KB + r) * VV] = av[r];
        }
        #pragma unroll
        for (int m = 0; m < 4; ++m) {
            u32x2 val;
            val.x = pkbf(av[4 * m + 0], av[4 * m + 1]);
            val.y = pkbf(av[4 * m + 2], av[4 * m + 3]);
            *(u32x2*)&a_sh[b][swz_idx(wl, vq * 16 + 4 * m)] = val;
        }
        *(uint4*)&y_sh[b][tid * 8] = yv;
    };
    auto compute = [&](int b) {
        const __bf16* ysh = y_sh[b];
        const __bf16* ash = a_sh[b];
        #pragma unroll
        for (int s = 0; s < 2; ++s) {
            const int k0 = s * 32 + kq;
            bf16x8 a0 = mkfrag(ysh, crow,      k0);
            bf16x8 a1 = mkfrag(ysh, crow + 16, k0);
            bf16x8 b0 = mkfrag(ash, wcol,      k0);
            bf16x8 b1 = mkfrag(ash, wcol + 16, k0);
            acc[0][0] = __builtin_amdgcn_mfma_f32_16x16x32_bf16(a0, b0, acc[0][0], 0, 0, 0);
            acc[0][1] = __builtin_amdgcn_mfma_f32_16x16x32_bf16(a0, b1, acc[0][1], 0, 0, 0);
            acc[1][0] = __builtin_amdgcn_mfma_f32_16x16x32_bf16(a1, b0, acc[1][0], 0, 0, 0);
            acc[1][1] = __builtin_amdgcn_mfma_f32_16x16x32_bf16(a1, b1, acc[1][1], 0, 0, 0);
        }
    };

    stage_load(0);
    stage_write(0, 0);
    __syncthreads();
    for (int t = 0; t < NCHUNK; ++t) {
        if (t + 1 < NCHUNK) stage_load(t + 1);
        compute(t & 1);
        if (t + 1 < NCHUNK) stage_write(t + 1, (t + 1) & 1);
        __syncthreads();
    }

    // epilogue: D layout col=lane&15, row=(lane>>4)*4+r  [verified m89/m91]
    float* po = out + ((size_t)n * CC) * VV + w0;
    #pragma unroll
    for (int mt = 0; mt < 2; ++mt)
        #pragma unroll
        for (int nt = 0; nt < 2; ++nt)
            #pragma unroll
            for (int r = 0; r < 4; ++r) {
                int c = mrow * 32 + mt * 16 + kq + r;
                int w = ncol * 32 + nt * 16 + l15;
                po[(size_t)c * VV + w] = acc[mt][nt][r];
            }
}

// K3 (only in tail-fallback mode): copy the A rows whose Acopy slots held y
__global__ __launch_bounds__(256) void k_tailcopy(const float* __restrict__ A,
                                                  float* __restrict__ Acopy,
                                                  size_t baseFloats, size_t count4) {
    size_t i = (size_t)blockIdx.x * 256 + threadIdx.x;
    if (i < count4) {
        f32x4 v = *(const f32x4*)(A + baseFloats + i * 4);
        *(f32x4*)(Acopy + baseFloats + i * 4) = v;
    }
}

extern "C" void kernel_launch(void* const* d_in, const int* in_sizes, int n_in,
                              void* d_out, int out_size, void* d_ws, size_t ws_size,
                              hipStream_t stream) {
    (void)in_sizes; (void)n_in; (void)out_size;
    const float* x = (const float*)d_in[0];
    const float* A = (const float*)d_in[1];
    const float* W = (const float*)d_in[2];
    const float* b = (const float*)d_in[3];
    float* out   = (float*)d_out;
    float* Acopy = out + (size_t)NB * CC * VV;

    const size_t yElems = (size_t)NB * NCHUNK * CC * KB;   // 2,097,152 bf16 = 4 MB
    __bf16* yws;
    int skipTail = 0;
    if (ws_size >= yElems * 2) {
        yws = (__bf16*)d_ws;
    } else {
        skipTail = 1;  // park y in the tail of the A-copy region (rows A[3][8064:])
        yws = (__bf16*)(Acopy + ((size_t)NB * VV * VV - yElems / 2));
    }

    hipLaunchKernelGGL(k_y,    dim3(NB * 16), dim3(256), 0, stream, x, W, b, yws);
    hipLaunchKernelGGL(k_main, dim3(NB * 64), dim3(512), 0, stream, A, yws, out, Acopy, skipTail);
    if (skipTail) {
        size_t base = (size_t)NB * VV * VV - yElems / 2;     // floats
        hipLaunchKernelGGL(k_tailcopy, dim3((unsigned)((yElems / 8 + 255) / 256)), dim3(256),
                           0, stream, A, Acopy, base, yElems / 8);
    }
}